// Round 4
// baseline (272.342 us; speedup 1.0000x reference)
//
#include <hip/hip_runtime.h>

#define B 256
#define T 2048
#define L 48
#define G 16           // segments per batch chain
#define SEG 128        // steps per segment (last: 127)
#define KNORM 4.371f   // per-step constant renorm: ln(48*e^0.5)
#define TOTALF (B * T * L)

typedef short v4s __attribute__((ext_vector_type(4)));
typedef short v8s __attribute__((ext_vector_type(8)));
typedef float v4f __attribute__((ext_vector_type(4)));
typedef int   v2i __attribute__((ext_vector_type(2)));

// Single-wave "barrier" (combine kernel only): drain LDS counters, not vmcnt.
#define WAVE_SYNC() asm volatile("s_waitcnt lgkmcnt(0)" ::: "memory")

#if __has_builtin(__builtin_amdgcn_mfma_f32_16x16x16bf16_1k)
#define MFMA16(a, b, c) __builtin_amdgcn_mfma_f32_16x16x16bf16_1k((a), (b), (c), 0, 0, 0)
#else
__device__ __forceinline__ v4f mfma16_asm(v4s a, v4s b, v4f c) {
    asm volatile("v_mfma_f32_16x16x16_bf16 %0, %1, %2, %0\n\ts_nop 7\n\ts_nop 7"
                 : "+v"(c) : "v"(a), "v"(b));
    return c;
}
#define MFMA16(a, b, c) mfma16_asm((a), (b), (c))
#endif

// gfx950 doubled-K bf16 MFMA with self-consistent sigma slot labeling
// (slot (q,e) == state row 4q+e for e<4, 16+4q+(e-4) for e>=4) shared by A
// and B, so the reduction is layout-invariant.  B-frag = concat of the two
// K=16-style state tiles: zero data movement.  (Verified correct in R3.)
#if __has_builtin(__builtin_amdgcn_mfma_f32_16x16x32_bf16)
typedef __bf16 v8y __attribute__((ext_vector_type(8)));
__device__ __forceinline__ v4f mfma32(v8s a, v8s b, v4f c) {
    return __builtin_amdgcn_mfma_f32_16x16x32_bf16(
        __builtin_bit_cast(v8y, a), __builtin_bit_cast(v8y, b), c, 0, 0, 0);
}
#else
__device__ __forceinline__ v4f mfma32(v8s a, v8s b, v4f c) {
    asm volatile("v_mfma_f32_16x16x32_bf16 %0, %1, %2, %0\n\ts_nop 7\n\ts_nop 7"
                 : "+v"(c) : "v"(a), "v"(b));
    return c;
}
#endif

// HW RNE pack: bf16(lo) -> bits 15:0, bf16(hi) -> bits 31:16 (T12 recipe).
__device__ __forceinline__ unsigned cvt_pk(float lo, float hi) {
    unsigned r;
    asm("v_cvt_pk_bf16_f32 %0, %1, %2" : "=v"(r) : "v"(lo), "v"(hi));
    return r;
}

// (C .* g) rounded to bf16 fragment: 4 mul + 2 cvt_pk
__device__ __forceinline__ v4s scale_pack(v4f cf, v4f g) {
    v4f a = cf * g;
    v2i d;
    d.x = (int)cvt_pk(a.x, a.y);
    d.y = (int)cvt_pk(a.z, a.w);
    return __builtin_bit_cast(v4s, d);
}

__device__ __forceinline__ v8s fuse01(v4s n0, v4s n1) {
    v2i a_ = __builtin_bit_cast(v2i, n0);
    v2i b_ = __builtin_bit_cast(v2i, n1);
    int4 fw; fw.x = a_.x; fw.y = a_.y; fw.z = b_.x; fw.w = b_.y;
    return __builtin_bit_cast(v8s, fw);
}

// ---------------------------------------------------------------------------
// Segment scan, column-split + ILP-2: workgroup (b,s) with s in 0..7 handles
// TWO segments (s, s+8); 192 threads = 3 waves; wave w owns 16-column slice
// ct=w of both Q_s and Q_{s+8}.  The two chains are data-independent, so each
// wave interleaves 12 MFMAs (6 per chain) per double-step: chain A's VALU
// repack hides under chain B's MFMAs and vice-versa (R3 showed the single
// chain is latency-bound: MfmaUtil 42%, VALUBusy 37%, wall 2.4x the MFMA
// pipe floor).  A-fragments (E^T), identity init, staging logic shared.
// Grid = B*8 = 2048 wgs = 24 waves/CU: whole grid resident in one batch.
// ---------------------------------------------------------------------------
__global__ __launch_bounds__(192, 6) void crf_scan(
    const float* __restrict__ em, const int* __restrict__ tags,
    const float* __restrict__ trans, float* __restrict__ out,
    float* __restrict__ ws)
{
    const int b   = blockIdx.x >> 3;
    const int s   = blockIdx.x & 7;
    const int tid = threadIdx.x;
    const int ct  = tid >> 6;          // wave = column tile 0..2
    const int ln  = tid & 63;
    const int q   = ln >> 4;           // 0..3
    const int c   = ln & 15;           // 0..15

    // 8 g-rows x 2 chains x 2 buffers
    __shared__ __align__(16) float smem[2 * 768];

    const size_t bem = (size_t)b * T * L;
    const int t0A = 1 + SEG * s;            // chain A: segment s   (always 128 steps)
    const int t0B = 1 + SEG * (s + 8);      // chain B: segment s+8 (127 steps when s==7)

    // A fragments of E^T = exp(trans)^T, shared by both chains.
    v8s A32[3];
    #pragma unroll
    for (int rt = 0; rt < 3; ++rt) {
        const int m = 16 * rt + c;
        uint4 aw;
        aw.x = cvt_pk(__expf(trans[(4 * q + 0) * L + m]),
                      __expf(trans[(4 * q + 1) * L + m]));
        aw.y = cvt_pk(__expf(trans[(4 * q + 2) * L + m]),
                      __expf(trans[(4 * q + 3) * L + m]));
        aw.z = cvt_pk(__expf(trans[(16 + 4 * q + 0) * L + m]),
                      __expf(trans[(16 + 4 * q + 1) * L + m]));
        aw.w = cvt_pk(__expf(trans[(16 + 4 * q + 2) * L + m]),
                      __expf(trans[(16 + 4 * q + 3) * L + m]));
        A32[rt] = __builtin_bit_cast(v8s, aw);
    }
    v4s A16[3];
    #pragma unroll
    for (int rt = 0; rt < 3; ++rt) {
        const int m = 16 * rt + c;
        v2i d;
        d.x = (int)cvt_pk(__expf(trans[(32 + 4 * q + 0) * L + m]),
                          __expf(trans[(32 + 4 * q + 1) * L + m]));
        d.y = (int)cvt_pk(__expf(trans[(32 + 4 * q + 2) * L + m]),
                          __expf(trans[(32 + 4 * q + 3) * L + m]));
        A16[rt] = __builtin_bit_cast(v4s, d);
    }

    // Identity init (same words for both chains).
    const int col = 16 * ct + c;
    v8s BqA01, BqB01;
    v4s BqA2, BqB2;
    {
        int4 w;
        w.x = (4 * q + 0 == col ? 0x3F80 : 0) | (4 * q + 1 == col ? 0x3F800000 : 0);
        w.y = (4 * q + 2 == col ? 0x3F80 : 0) | (4 * q + 3 == col ? 0x3F800000 : 0);
        w.z = (16 + 4 * q + 0 == col ? 0x3F80 : 0) | (16 + 4 * q + 1 == col ? 0x3F800000 : 0);
        w.w = (16 + 4 * q + 2 == col ? 0x3F80 : 0) | (16 + 4 * q + 3 == col ? 0x3F800000 : 0);
        BqA01 = __builtin_bit_cast(v8s, w);
        BqB01 = BqA01;
        v2i d2;
        d2.x = (32 + 4 * q + 0 == col ? 0x3F80 : 0) | (32 + 4 * q + 1 == col ? 0x3F800000 : 0);
        d2.y = (32 + 4 * q + 2 == col ? 0x3F80 : 0) | (32 + 4 * q + 3 == col ? 0x3F800000 : 0);
        BqA2 = __builtin_bit_cast(v4s, d2);
        BqB2 = BqA2;
    }

    const v4f zero4 = {0.f, 0.f, 0.f, 0.f};   // persistent C-in

    // Interleaved double-step: 12 MFMAs + 2 repacks; chains independent.
    auto do_step2 = [&](const float* rpA, const float* rpB, bool commitB) {
        v4f a0 = mfma32(A32[0], BqA01, zero4);
        v4f b0 = mfma32(A32[0], BqB01, zero4);
        v4f a1 = mfma32(A32[1], BqA01, zero4);
        v4f b1 = mfma32(A32[1], BqB01, zero4);
        v4f a2 = mfma32(A32[2], BqA01, zero4);
        v4f b2 = mfma32(A32[2], BqB01, zero4);
        a0 = MFMA16(A16[0], BqA2, a0);
        b0 = MFMA16(A16[0], BqB2, b0);
        a1 = MFMA16(A16[1], BqA2, a1);
        b1 = MFMA16(A16[1], BqB2, b1);
        a2 = MFMA16(A16[2], BqA2, a2);
        b2 = MFMA16(A16[2], BqB2, b2);

        v4f gA0 = *(const v4f*)(rpA + 4 * q);
        v4f gA1 = *(const v4f*)(rpA + 16 + 4 * q);
        v4f gA2 = *(const v4f*)(rpA + 32 + 4 * q);
        BqA01 = fuse01(scale_pack(a0, gA0), scale_pack(a1, gA1));
        BqA2  = scale_pack(a2, gA2);

        v4f gB0 = *(const v4f*)(rpB + 4 * q);
        v4f gB1 = *(const v4f*)(rpB + 16 + 4 * q);
        v4f gB2 = *(const v4f*)(rpB + 32 + 4 * q);
        v4s nB0 = scale_pack(b0, gB0);
        v4s nB1 = scale_pack(b1, gB1);
        v4s nB2 = scale_pack(b2, gB2);
        if (commitB) {                 // wg-uniform; false only for the final
            BqB01 = fuse01(nB0, nB1);  // step of segment 15 (s==7, bk==15, k==7)
            BqB2  = nB2;
        }
    };

    // stage g-rows t0..t0+7 for both chains into buffer 0
    {
        size_t gfA = bem + (size_t)t0A * L;
        size_t gfB = bem + (size_t)t0B * L;
        smem[tid]             = __expf(em[gfA + tid]       - KNORM);
        smem[tid + 192]       = __expf(em[gfA + tid + 192] - KNORM);
        smem[384 + tid]       = __expf(em[gfB + tid]       - KNORM);
        smem[384 + tid + 192] = __expf(em[gfB + tid + 192] - KNORM);
        __syncthreads();
    }

    for (int bk = 0; bk < 16; ++bk) {
        const float* cur = smem + (bk & 1) * 768;
        float* nxt = smem + ((bk & 1) ^ 1) * 768;

        // prefetch next 8 g-rows per chain (A always in-range; B clamp
        // protects only the absolute tensor end, b=255/s=7)
        size_t gfA = bem + (size_t)(t0A + 8 * (bk + 1)) * L;
        size_t gfB = bem + (size_t)(t0B + 8 * (bk + 1)) * L;
        if (gfB > (size_t)TOTALF - 384) gfB = (size_t)TOTALF - 384;
        float sA0 = em[gfA + tid];
        float sA1 = em[gfA + tid + 192];
        float sB0 = em[gfB + tid];
        float sB1 = em[gfB + tid + 192];

        #pragma unroll
        for (int k = 0; k < 8; ++k) {
            bool commitB = (t0B + 8 * bk + k < T);   // wg-uniform guard
            do_step2(cur + 48 * k, cur + 384 + 48 * k, commitB);
        }

        nxt[tid]             = __expf(sA0 - KNORM);
        nxt[tid + 192]       = __expf(sA1 - KNORM);
        nxt[384 + tid]       = __expf(sB0 - KNORM);
        nxt[384 + tid + 192] = __expf(sB1 - KNORM);
        __syncthreads();
    }

    // store both 16-col slices of Q_s and Q_{s+8}, bf16 row-major [row*48+col]
    {
        unsigned short* qsA = (unsigned short*)ws + (size_t)(b * G + s) * 2304;
        unsigned short* qsB = (unsigned short*)ws + (size_t)(b * G + s + 8) * 2304;
        int4 wA = __builtin_bit_cast(int4, BqA01);
        int4 wB = __builtin_bit_cast(int4, BqB01);
        v2i dA2 = __builtin_bit_cast(v2i, BqA2);
        v2i dB2 = __builtin_bit_cast(v2i, BqB2);
        int rows[3] = {4 * q, 16 + 4 * q, 32 + 4 * q};
        int aw[3][2] = {{wA.x, wA.y}, {wA.z, wA.w}, {dA2.x, dA2.y}};
        int bw[3][2] = {{wB.x, wB.y}, {wB.z, wB.w}, {dB2.x, dB2.y}};
        #pragma unroll
        for (int kt = 0; kt < 3; ++kt) {
            int r0 = rows[kt];
            unsigned x = (unsigned)aw[kt][0], y = (unsigned)aw[kt][1];
            qsA[(r0 + 0) * 48 + col] = (unsigned short)(x & 0xffffu);
            qsA[(r0 + 1) * 48 + col] = (unsigned short)(x >> 16);
            qsA[(r0 + 2) * 48 + col] = (unsigned short)(y & 0xffffu);
            qsA[(r0 + 3) * 48 + col] = (unsigned short)(y >> 16);
            x = (unsigned)bw[kt][0]; y = (unsigned)bw[kt][1];
            qsB[(r0 + 0) * 48 + col] = (unsigned short)(x & 0xffffu);
            qsB[(r0 + 1) * 48 + col] = (unsigned short)(x >> 16);
            qsB[(r0 + 2) * 48 + col] = (unsigned short)(y & 0xffffu);
            qsB[(r0 + 3) * 48 + col] = (unsigned short)(y >> 16);
        }
    }

    // fused gold score: this wg covers t in [128s,128s+128) u [128(s+8),+128)
    const int* tg = tags + (size_t)b * T;
    float gp = 0.f;
    if (tid < 128) {
        #pragma unroll
        for (int hh = 0; hh < 2; ++hh) {
            int t = SEG * (s + 8 * hh) + tid;
            int tag = tg[t];
            gp += em[bem + (size_t)t * L + tag];
            if (t < T - 1)  gp += trans[tag * L + tg[t + 1]];
            if (t == 0)     gp += trans[tag];
            if (t == T - 1) gp += trans[tag * L + (L - 1)];
        }
    }
    #pragma unroll
    for (int off = 32; off; off >>= 1) gp += __shfl_xor(gp, off);
    __shared__ float red[3];
    if (ln == 0) red[ct] = gp;
    __syncthreads();
    if (tid == 0) atomicAdd(out, -(red[0] + red[1] + red[2]));
}

// ---------------------------------------------------------------------------
// Combine: per batch, u = alpha_0; for s: u = Q_s u (renormed, bf16 rows,
// next-segment register prefetch); Z_b = log(sum u_i E[i][end]) + 2047*K +
// accumulated renorm logs.  Lane l owns row l => no cross-lane reduce.
// ---------------------------------------------------------------------------
__global__ __launch_bounds__(64) void crf_combine(
    const float* __restrict__ em, const float* __restrict__ trans,
    const float* __restrict__ ws, float* __restrict__ out)
{
    const int b = blockIdx.x, l = threadIdx.x;
    const int lc = (l < L) ? l : (L - 1);

    __shared__ float us[64];

    const unsigned short* qb = (const unsigned short*)ws + (size_t)b * G * 2304;

    float u = (l < L) ? __expf(trans[l] + em[(size_t)b * T * L + l]) : 0.f;
    float logtot = 2047.0f * KNORM;

    uint4 pre[6];
    {
        const uint4* p = (const uint4*)(qb + lc * 48);
        #pragma unroll
        for (int ii = 0; ii < 6; ++ii) pre[ii] = p[ii];
    }

    for (int s = 0; s < G; ++s) {
        us[l] = u;
        uint4 cur[6];
        #pragma unroll
        for (int ii = 0; ii < 6; ++ii) cur[ii] = pre[ii];
        if (s + 1 < G) {
            const uint4* p = (const uint4*)(qb + (size_t)(s + 1) * 2304 + lc * 48);
            #pragma unroll
            for (int ii = 0; ii < 6; ++ii) pre[ii] = p[ii];
        }
        WAVE_SYNC();

        float acc = 0.f;
        #pragma unroll
        for (int ii = 0; ii < 6; ++ii) {
            unsigned w0 = cur[ii].x, w1 = cur[ii].y, w2 = cur[ii].z, w3 = cur[ii].w;
            int jj = ii * 8;
            acc = fmaf(__uint_as_float(w0 << 16),          us[jj + 0], acc);
            acc = fmaf(__uint_as_float(w0 & 0xffff0000u),  us[jj + 1], acc);
            acc = fmaf(__uint_as_float(w1 << 16),          us[jj + 2], acc);
            acc = fmaf(__uint_as_float(w1 & 0xffff0000u),  us[jj + 3], acc);
            acc = fmaf(__uint_as_float(w2 << 16),          us[jj + 4], acc);
            acc = fmaf(__uint_as_float(w2 & 0xffff0000u),  us[jj + 5], acc);
            acc = fmaf(__uint_as_float(w3 << 16),          us[jj + 6], acc);
            acc = fmaf(__uint_as_float(w3 & 0xffff0000u),  us[jj + 7], acc);
        }
        WAVE_SYNC();   // us reads done before next overwrite

        float r = __int_as_float(
            __builtin_amdgcn_readlane(__float_as_int(acc), 0));
        logtot += __logf(r);
        u = (l < L) ? acc * __builtin_amdgcn_rcpf(r) : 0.f;
    }

    float v = (l < L) ? u * __expf(trans[lc * L + (L - 1)]) : 0.f;
    #pragma unroll
    for (int off = 32; off; off >>= 1) v += __shfl_xor(v, off);
    if (l == 0) atomicAdd(out, logtot + __logf(v));
}

extern "C" void kernel_launch(void* const* d_in, const int* in_sizes, int n_in,
                              void* d_out, int out_size, void* d_ws, size_t ws_size,
                              hipStream_t stream) {
    const float* em    = (const float*)d_in[0];   // (B, T, L) f32
    const int*   tags  = (const int*)  d_in[1];   // (B, T) i32
    const float* trans = (const float*)d_in[2];   // (L, L) f32
    float* out = (float*)d_out;
    float* ws  = (float*)d_ws;                    // 4096 * 2304 bf16 = 18.9 MB

    (void)hipMemsetAsync(out, 0, sizeof(float), stream);
    crf_scan   <<<B * 8, 192, 0, stream>>>(em, tags, trans, out, ws);
    crf_combine<<<B,     64, 0, stream>>>(em, trans, ws, out);
}